// Round 7
// baseline (307.296 us; speedup 1.0000x reference)
//
#include <hip/hip_runtime.h>
#include <hip/hip_bf16.h>

// Problem constants
#define NROWS 8192   // 2B
#define BHALF 4096   // B
#define DDIM  512    // D

// GEMM tiling: 256x256 tile, 8 waves (2M x 4N), BK=64, 4-phase counted-vmcnt
#define BM 256
#define BK 64
#define KT (DDIM / BK)             // 8 K-tiles
#define NT (NROWS / BM)            // 32 tiles per side
#define NTRI (NT * (NT + 1) / 2)   // 528 upper-triangle tiles
#define CPX (NTRI / 8)             // 66 (528 % 8 == 0 -> bijective XCD remap)

// sqrt(1/0.07): fold temperature into the normalized features.
#define FSCALE 3.7796447300922722f

typedef short bf16x8 __attribute__((ext_vector_type(8)));
typedef float f32x4 __attribute__((ext_vector_type(4)));
typedef unsigned short u16x8 __attribute__((ext_vector_type(8)));
typedef __attribute__((address_space(1))) unsigned int gu32;
typedef __attribute__((address_space(3))) unsigned int lu32;

#define MFMA_(a, b, c) __builtin_amdgcn_mfma_f32_16x16x32_bf16(a, b, c, 0, 0, 0)
#define VMCNT(N) asm volatile("s_waitcnt vmcnt(" #N ")" ::: "memory")
#define LGKM0                                            \
  do {                                                   \
    asm volatile("s_waitcnt lgkmcnt(0)" ::: "memory");   \
    __builtin_amdgcn_sched_barrier(0);                   \
  } while (0)
#define BAR                                              \
  do {                                                   \
    __builtin_amdgcn_sched_barrier(0);                   \
    __builtin_amdgcn_s_barrier();                        \
    __builtin_amdgcn_sched_barrier(0);                   \
  } while (0)

// ---------------------------------------------------------------------------
// Kernel 1: L2-normalize rows of concat([logits,label]); store bf16 * FSCALE.
// Also zeroes rowsum (blocks 0..7) and the done-counter (block 8).
// ---------------------------------------------------------------------------
__global__ __launch_bounds__(256) void normalize_kernel(
    const float* __restrict__ logits, const float* __restrict__ label,
    unsigned short* __restrict__ fn, float* __restrict__ rowsum, int* ctr) {
  if (blockIdx.x < 8)
    ((float4*)rowsum)[blockIdx.x * 256 + threadIdx.x] =
        make_float4(0.f, 0.f, 0.f, 0.f);
  if (blockIdx.x == 8 && threadIdx.x == 0) *ctr = 0;

  const int w = threadIdx.x >> 6, lane = threadIdx.x & 63;
  const int row = blockIdx.x * 4 + w;
  const float* src = (row < BHALF) ? (logits + (size_t)row * DDIM)
                                   : (label + (size_t)(row - BHALF) * DDIM);
  const float4* s4 = (const float4*)src;
  float4 a = s4[lane * 2 + 0];
  float4 b = s4[lane * 2 + 1];
  float ss = a.x * a.x + a.y * a.y + a.z * a.z + a.w * a.w +
             b.x * b.x + b.y * b.y + b.z * b.z + b.w * b.w;
#pragma unroll
  for (int m = 1; m < 64; m <<= 1) ss += __shfl_xor(ss, m);
  const float inv = FSCALE / fmaxf(sqrtf(ss), 1e-12f);
  const float v[8] = {a.x, a.y, a.z, a.w, b.x, b.y, b.z, b.w};
  u16x8 o;
#pragma unroll
  for (int j = 0; j < 8; ++j) {
    float x = v[j] * inv;
    unsigned u = __float_as_uint(x);
    unsigned r = (u + 0x7fffu + ((u >> 16) & 1u)) >> 16;  // RNE to bf16
    o[j] = (unsigned short)r;
  }
  *(u16x8*)(fn + (size_t)row * DDIM + lane * 8) = o;
}

// ---------------------------------------------------------------------------
// Kernel 2: EXACT round-4 structure (single instantiation, 528 full tiles,
// everything at kernel scope) + ONE delta: fused last-block loss reduction.
// 8-phase counted-vmcnt schedule (T3+T4), setprio (T5), XOR-swizzle (T2),
// XCD-contiguous remap (T1).
// ---------------------------------------------------------------------------
__global__ __launch_bounds__(512) void simexp_tri_kernel(
    const unsigned short* __restrict__ fn, float* __restrict__ rowsum,
    float* __restrict__ pos, int* __restrict__ ctr, float* __restrict__ out) {
  extern __shared__ char lds[];  // 2 bufs x (A 32KB | B 32KB) = 128 KB
  __shared__ float lds_rsum[BM];
  __shared__ float lds_csum[BM];
  __shared__ int is_last;

  // XCD remap, then triangle index -> (rm, cn) from bottom-right.
  const int bid0 = (int)blockIdx.x;
  const int bid = (bid0 & 7) * CPX + (bid0 >> 3);
  const int u = (NTRI - 1) - bid;
  int k = (int)((sqrtf(8.f * (float)u + 1.f) - 1.f) * 0.5f);
  while ((k + 1) * (k + 2) / 2 <= u) ++k;
  while (k * (k + 1) / 2 > u) --k;
  const int rm = (NT - 1) - k;
  const int cn = (NT - 1) - (u - k * (k + 1) / 2);
  const int rowBase = rm * BM, colBase = cn * BM;
  const bool diag = (rm == cn);
  const bool posTile = (cn == rm + NT / 2);

  const int tid = threadIdx.x;
  const int w = tid >> 6, lane = tid & 63;
  const int wr = w >> 2, wc = w & 3;   // wave grid 2x4; wave owns 128x64 of C
  const int l15 = lane & 15, l4 = lane >> 4;

  if (tid < BM) { lds_rsum[tid] = 0.f; lds_csum[tid] = 0.f; }

  const int r8 = lane >> 3;
  const int sw16 = ((lane & 7) ^ r8) << 4;

  auto stageA = [&](int d, int kk, int R) {
    const char* g =
        (const char*)(fn + (size_t)(rowBase + R + w * 8 + r8) * DDIM + kk) + sw16;
    __builtin_amdgcn_global_load_lds(
        (gu32*)g, (lu32*)(lds + d * 65536 + (R + w * 8) * 128), 16, 0, 0);
  };
  auto stageB = [&](int d, int kk, int R) {
    const char* g =
        (const char*)(fn + (size_t)(colBase + R + w * 8 + r8) * DDIM + kk) + sw16;
    __builtin_amdgcn_global_load_lds(
        (gu32*)g, (lu32*)(lds + d * 65536 + 32768 + (R + w * 8) * 128), 16, 0, 0);
  };
  auto readA = [&](int d, int m, int ks) -> bf16x8 {
    const int r = wr * 128 + m * 16 + l15;
    return *(const bf16x8*)(lds + d * 65536 + r * 128 +
                            (((ks * 4 + l4) ^ (r & 7)) << 4));
  };
  auto readB = [&](int d, int n, int ks) -> bf16x8 {
    const int r = wc * 64 + n * 16 + l15;
    return *(const bf16x8*)(lds + d * 65536 + 32768 + r * 128 +
                            (((ks * 4 + l4) ^ (r & 7)) << 4));
  };

  f32x4 acc[8][4];
#pragma unroll
  for (int m = 0; m < 8; ++m)
#pragma unroll
    for (int n = 0; n < 4; ++n) acc[m][n] = (f32x4){0.f, 0.f, 0.f, 0.f};

#define PHASE0(STAGES)                                                    \
  {                                                                       \
    _Pragma("unroll") for (int n = 0; n < 4; ++n) {                       \
      bf[n][0] = readB(d, n, 0);                                          \
      bf[n][1] = readB(d, n, 1);                                          \
    }                                                                     \
    bf16x8 a00 = readA(d, 0, 0), a01 = readA(d, 0, 1);                    \
    bf16x8 a10 = readA(d, 1, 0), a11 = readA(d, 1, 1);                    \
    STAGES;                                                               \
    BAR;                                                                  \
    LGKM0;                                                                \
    __builtin_amdgcn_s_setprio(1);                                        \
    _Pragma("unroll") for (int n = 0; n < 4; ++n) {                       \
      acc[0][n] = MFMA_(a00, bf[n][0], acc[0][n]);                        \
      acc[1][n] = MFMA_(a10, bf[n][0], acc[1][n]);                        \
    }                                                                     \
    _Pragma("unroll") for (int n = 0; n < 4; ++n) {                       \
      acc[0][n] = MFMA_(a01, bf[n][1], acc[0][n]);                        \
      acc[1][n] = MFMA_(a11, bf[n][1], acc[1][n]);                        \
    }                                                                     \
    __builtin_amdgcn_s_setprio(0);                                        \
    BAR;                                                                  \
  }

#define PHASE(P, STAGES, TAILWAIT)                                        \
  {                                                                       \
    bf16x8 a00 = readA(d, 2 * (P), 0), a01 = readA(d, 2 * (P), 1);        \
    bf16x8 a10 = readA(d, 2 * (P) + 1, 0), a11 = readA(d, 2 * (P) + 1, 1);\
    STAGES;                                                               \
    BAR;                                                                  \
    LGKM0;                                                                \
    __builtin_amdgcn_s_setprio(1);                                        \
    _Pragma("unroll") for (int n = 0; n < 4; ++n) {                       \
      acc[2 * (P)][n] = MFMA_(a00, bf[n][0], acc[2 * (P)][n]);            \
      acc[2 * (P) + 1][n] = MFMA_(a10, bf[n][0], acc[2 * (P) + 1][n]);    \
    }                                                                     \
    _Pragma("unroll") for (int n = 0; n < 4; ++n) {                       \
      acc[2 * (P)][n] = MFMA_(a01, bf[n][1], acc[2 * (P)][n]);            \
      acc[2 * (P) + 1][n] = MFMA_(a11, bf[n][1], acc[2 * (P) + 1][n]);    \
    }                                                                     \
    __builtin_amdgcn_s_setprio(0);                                        \
    TAILWAIT;                                                             \
    BAR;                                                                  \
  }

  // Prologue: stage tile 0 in wait-order; leave A@64,A@192 in flight.
  stageB(0, 0, 0);  stageB(0, 0, 64); stageB(0, 0, 128); stageB(0, 0, 192);
  stageA(0, 0, 0);  stageA(0, 0, 128);
  stageA(0, 0, 64); stageA(0, 0, 192);
  VMCNT(2);
  BAR;

  for (int t = 0; t < KT - 1; ++t) {
    const int d = t & 1, o = d ^ 1;
    const int kn = (t + 1) * BK;
    bf16x8 bf[4][2];
    PHASE0(stageB(o, kn, 0); stageB(o, kn, 64));
    PHASE(1, stageB(o, kn, 128); stageB(o, kn, 192), VMCNT(4));
    PHASE(2, stageA(o, kn, 0); stageA(o, kn, 128), (void)0);
    PHASE(3, stageA(o, kn, 64); stageA(o, kn, 192), VMCNT(2));
  }
  {  // peeled last tile: no staging; drain A@64,A@192 before P2.
    const int d = (KT - 1) & 1;
    bf16x8 bf[4][2];
    PHASE0((void)0);
    PHASE(1, (void)0, VMCNT(0));
    PHASE(2, (void)0, (void)0);
    PHASE(3, (void)0, (void)0);
  }
#undef PHASE0
#undef PHASE

  // Epilogue. C frag layout: col = l15, row = l4*4 + j (verified r1-r6).
  float rs[8][4];
  float cs[4];
#pragma unroll
  for (int m = 0; m < 8; ++m)
#pragma unroll
    for (int j = 0; j < 4; ++j) rs[m][j] = 0.f;
#pragma unroll
  for (int n = 0; n < 4; ++n) cs[n] = 0.f;

#pragma unroll
  for (int m = 0; m < 8; ++m)
#pragma unroll
    for (int n = 0; n < 4; ++n)
#pragma unroll
      for (int j = 0; j < 4; ++j) {
        const int rl = wr * 128 + m * 16 + l4 * 4 + j;  // local row
        const int cl = wc * 64 + n * 16 + l15;          // local col
        const float v = acc[m][n][j];
        float e = __expf(v);
        if (diag && rl == cl) e = 0.f;  // mask self-similarity
        rs[m][j] += e;
        cs[n] += e;
        if (posTile && rl == cl) pos[rowBase + rl] = v;  // sim[i, i+B]/T
      }

#pragma unroll
  for (int m = 0; m < 8; ++m)
#pragma unroll
    for (int j = 0; j < 4; ++j) {
      float s = rs[m][j];
      s += __shfl_xor(s, 1);
      s += __shfl_xor(s, 2);
      s += __shfl_xor(s, 4);
      s += __shfl_xor(s, 8);
      if (l15 == 0)
        atomicAdd(&lds_rsum[wr * 128 + m * 16 + l4 * 4 + j], s);
    }
  if (!diag) {
#pragma unroll
    for (int n = 0; n < 4; ++n) {
      float s = cs[n];
      s += __shfl_xor(s, 16);
      s += __shfl_xor(s, 32);
      if (l4 == 0) atomicAdd(&lds_csum[wc * 64 + n * 16 + l15], s);
    }
  }
  __syncthreads();
  if (tid < BM) {
    atomicAdd(&rowsum[rowBase + tid], lds_rsum[tid]);
    if (!diag) atomicAdd(&rowsum[colBase + tid], lds_csum[tid]);
  }

  // ---- THE ONE DELTA vs r4: fused last-block loss reduction ----
  __threadfence();  // make this block's rowsum/pos writes device-visible
  if (tid == 0) {
    const int done = __hip_atomic_fetch_add(ctr, 1, __ATOMIC_ACQ_REL,
                                            __HIP_MEMORY_SCOPE_AGENT);
    is_last = (done == NTRI - 1);
  }
  __syncthreads();
  if (!is_last) return;

  float a = 0.f;
  for (int i = tid; i < NROWS; i += 512) {
    const float r = __hip_atomic_load(&rowsum[i], __ATOMIC_RELAXED,
                                      __HIP_MEMORY_SCOPE_AGENT);
    const float p = __hip_atomic_load(&pos[i & (BHALF - 1)], __ATOMIC_RELAXED,
                                      __HIP_MEMORY_SCOPE_AGENT);
    a += __logf(r) - p;
  }
#pragma unroll
  for (int m = 1; m < 64; m <<= 1) a += __shfl_xor(a, m);
  if (lane == 0) lds_rsum[w] = a;
  __syncthreads();
  if (tid == 0) {
    float t = 0.f;
#pragma unroll
    for (int i = 0; i < 8; ++i) t += lds_rsum[i];
    out[0] = t * (1.0f / NROWS);
  }
}

// ---------------------------------------------------------------------------
extern "C" void kernel_launch(void* const* d_in, const int* in_sizes, int n_in,
                              void* d_out, int out_size, void* d_ws, size_t ws_size,
                              hipStream_t stream) {
  const float* logits = (const float*)d_in[0];
  const float* label = (const float*)d_in[1];
  float* out = (float*)d_out;
  unsigned short* fn = (unsigned short*)d_ws;                        // 8 MB bf16
  float* rowsum = (float*)((char*)d_ws + (size_t)NROWS * DDIM * 2);  // 32 KB
  float* pos = rowsum + NROWS;                                       // 16 KB
  int* ctr = (int*)(pos + BHALF);

  normalize_kernel<<<NROWS / 4, 256, 0, stream>>>(logits, label, fn, rowsum, ctr);
  simexp_tri_kernel<<<NTRI, 512, 2 * 65536, stream>>>(fn, rowsum, pos, ctr, out);
}

// Round 9
// 124.463 us; speedup vs baseline: 2.4690x; 2.4690x over previous
//
#include <hip/hip_runtime.h>
#include <hip/hip_bf16.h>

// Problem constants
#define NROWS 8192   // 2B
#define BHALF 4096   // B
#define DDIM  512    // D

// GEMM tiling: 256-row tiles, BK=64, 8 waves (2Mx4N), 4-phase counted-vmcnt
#define BM 256
#define BK 64
#define KT (DDIM / BK)             // 8 K-tiles
#define NT (NROWS / BM)            // 32 tiles per side
#define NTRI (NT * (NT + 1) / 2)   // 528 upper-triangle tiles
#define NFULL 512                  // full 256x256 blocks (2 exact CU rounds)
#define NHALFB 32                  // 16 leftover tiles x 2 N-halves (256x128)
#define GRID (NFULL + NHALFB)      // 544

// sqrt(1/0.07): fold temperature into the normalized features.
#define FSCALE 3.7796447300922722f

typedef short bf16x8 __attribute__((ext_vector_type(8)));
typedef float f32x4 __attribute__((ext_vector_type(4)));
typedef unsigned short u16x8 __attribute__((ext_vector_type(8)));
typedef __attribute__((address_space(1))) unsigned int gu32;
typedef __attribute__((address_space(3))) unsigned int lu32;

#define MFMA_(a, b, c) __builtin_amdgcn_mfma_f32_16x16x32_bf16(a, b, c, 0, 0, 0)
#define VMCNT(N) asm volatile("s_waitcnt vmcnt(" #N ")" ::: "memory")
#define LGKM0                                            \
  do {                                                   \
    asm volatile("s_waitcnt lgkmcnt(0)" ::: "memory");   \
    __builtin_amdgcn_sched_barrier(0);                   \
  } while (0)
#define BAR                                              \
  do {                                                   \
    __builtin_amdgcn_sched_barrier(0);                   \
    __builtin_amdgcn_s_barrier();                        \
    __builtin_amdgcn_sched_barrier(0);                   \
  } while (0)

// ---------------------------------------------------------------------------
// Kernel 1: L2-normalize rows of concat([logits,label]); store bf16 * FSCALE.
// Also zeroes rowsum (blocks 0..7) and out (block 8). NO fences/counters.
// ---------------------------------------------------------------------------
__global__ __launch_bounds__(256) void normalize_kernel(
    const float* __restrict__ logits, const float* __restrict__ label,
    unsigned short* __restrict__ fn, float* __restrict__ rowsum,
    float* __restrict__ out) {
  if (blockIdx.x < 8)
    ((float4*)rowsum)[blockIdx.x * 256 + threadIdx.x] =
        make_float4(0.f, 0.f, 0.f, 0.f);
  if (blockIdx.x == 8 && threadIdx.x == 0) out[0] = 0.f;

  const int w = threadIdx.x >> 6, lane = threadIdx.x & 63;
  const int row = blockIdx.x * 4 + w;
  const float* src = (row < BHALF) ? (logits + (size_t)row * DDIM)
                                   : (label + (size_t)(row - BHALF) * DDIM);
  const float4* s4 = (const float4*)src;
  float4 a = s4[lane * 2 + 0];
  float4 b = s4[lane * 2 + 1];
  float ss = a.x * a.x + a.y * a.y + a.z * a.z + a.w * a.w +
             b.x * b.x + b.y * b.y + b.z * b.z + b.w * b.w;
#pragma unroll
  for (int m = 1; m < 64; m <<= 1) ss += __shfl_xor(ss, m);
  const float inv = FSCALE / fmaxf(sqrtf(ss), 1e-12f);
  const float v[8] = {a.x, a.y, a.z, a.w, b.x, b.y, b.z, b.w};
  u16x8 o;
#pragma unroll
  for (int j = 0; j < 8; ++j) {
    float x = v[j] * inv;
    unsigned u = __float_as_uint(x);
    unsigned r = (u + 0x7fffu + ((u >> 16) & 1u)) >> 16;  // RNE to bf16
    o[j] = (unsigned short)r;
  }
  *(u16x8*)(fn + (size_t)row * DDIM + lane * 8) = o;
}

// ---------------------------------------------------------------------------
// Tile body, templated on BN_ (256 = full tile, 128 = N-half tile).
// All __shared__ declared inside (addrspace(3) statically known -> ds_read).
// Waits (oldest-first queue):
//   full : end-P1 vmcnt(4), end-P3 vmcnt(2)
//   half : end-P1 vmcnt(2), end-P3 vmcnt(2)
// ---------------------------------------------------------------------------
template <int BN_>
__device__ __attribute__((always_inline)) void tile_body(
    const unsigned short* __restrict__ fn, float* __restrict__ rowsum,
    float* __restrict__ pos, int rowBase, int colBase) {
  extern __shared__ char lds[];  // 2 x (A 32KB | B BN_*128) double buffer
  __shared__ float lds_rsum[BM];
  __shared__ float lds_csum[BM];
  constexpr int NFRAG = BN_ / 64;             // B n-frags per wave
  constexpr int BUFSZ = 32768 + BN_ * 128;    // 64KB full / 48KB half

  const int tid = threadIdx.x;
  const int w = tid >> 6, lane = tid & 63;
  const int wr = w >> 2, wc = w & 3;  // wave grid 2x4; wave owns 128 x BN_/4
  const int l15 = lane & 15, l4 = lane >> 4;
  const int r8 = lane >> 3;
  const int sw16 = ((lane & 7) ^ r8) << 4;  // pre-swizzled global slot

  if (tid < BM) {
    lds_rsum[tid] = 0.f;
    lds_csum[tid] = 0.f;
  }

  auto stageA = [&](int d, int kk, int R) {
    const char* g =
        (const char*)(fn + (size_t)(rowBase + R + w * 8 + r8) * DDIM + kk) + sw16;
    __builtin_amdgcn_global_load_lds(
        (gu32*)g, (lu32*)(lds + d * BUFSZ + (R + w * 8) * 128), 16, 0, 0);
  };
  auto stageB = [&](int d, int kk, int R) {
    const char* g =
        (const char*)(fn + (size_t)(colBase + R + w * 8 + r8) * DDIM + kk) + sw16;
    __builtin_amdgcn_global_load_lds(
        (gu32*)g, (lu32*)(lds + d * BUFSZ + 32768 + (R + w * 8) * 128), 16, 0, 0);
  };
  auto readA = [&](int d, int m, int ks) -> bf16x8 {
    const int r = wr * 128 + m * 16 + l15;
    return *(const bf16x8*)(lds + d * BUFSZ + r * 128 +
                            (((ks * 4 + l4) ^ (r & 7)) << 4));
  };
  auto readB = [&](int d, int n, int ks) -> bf16x8 {
    const int r = wc * (BN_ / 4) + n * 16 + l15;
    return *(const bf16x8*)(lds + d * BUFSZ + 32768 + r * 128 +
                            (((ks * 4 + l4) ^ (r & 7)) << 4));
  };

  f32x4 acc[8][NFRAG];
#pragma unroll
  for (int m = 0; m < 8; ++m)
#pragma unroll
    for (int n = 0; n < NFRAG; ++n) acc[m][n] = (f32x4){0.f, 0.f, 0.f, 0.f};

#define PHASE0(STAGES)                                                    \
  {                                                                       \
    _Pragma("unroll") for (int n = 0; n < NFRAG; ++n) {                   \
      bf[n][0] = readB(d, n, 0);                                          \
      bf[n][1] = readB(d, n, 1);                                          \
    }                                                                     \
    bf16x8 a00 = readA(d, 0, 0), a01 = readA(d, 0, 1);                    \
    bf16x8 a10 = readA(d, 1, 0), a11 = readA(d, 1, 1);                    \
    STAGES;                                                               \
    BAR;                                                                  \
    LGKM0;                                                                \
    __builtin_amdgcn_s_setprio(1);                                        \
    _Pragma("unroll") for (int n = 0; n < NFRAG; ++n) {                   \
      acc[0][n] = MFMA_(a00, bf[n][0], acc[0][n]);                        \
      acc[1][n] = MFMA_(a10, bf[n][0], acc[1][n]);                        \
    }                                                                     \
    _Pragma("unroll") for (int n = 0; n < NFRAG; ++n) {                   \
      acc[0][n] = MFMA_(a01, bf[n][1], acc[0][n]);                        \
      acc[1][n] = MFMA_(a11, bf[n][1], acc[1][n]);                        \
    }                                                                     \
    __builtin_amdgcn_s_setprio(0);                                        \
    BAR;                                                                  \
  }

#define PHASE(P, STAGES, TAILWAIT)                                        \
  {                                                                       \
    bf16x8 a00 = readA(d, 2 * (P), 0), a01 = readA(d, 2 * (P), 1);        \
    bf16x8 a10 = readA(d, 2 * (P) + 1, 0), a11 = readA(d, 2 * (P) + 1, 1);\
    STAGES;                                                               \
    BAR;                                                                  \
    LGKM0;                                                                \
    __builtin_amdgcn_s_setprio(1);                                        \
    _Pragma("unroll") for (int n = 0; n < NFRAG; ++n) {                   \
      acc[2 * (P)][n] = MFMA_(a00, bf[n][0], acc[2 * (P)][n]);            \
      acc[2 * (P) + 1][n] = MFMA_(a10, bf[n][0], acc[2 * (P) + 1][n]);    \
    }                                                                     \
    _Pragma("unroll") for (int n = 0; n < NFRAG; ++n) {                   \
      acc[2 * (P)][n] = MFMA_(a01, bf[n][1], acc[2 * (P)][n]);            \
      acc[2 * (P) + 1][n] = MFMA_(a11, bf[n][1], acc[2 * (P) + 1][n]);    \
    }                                                                     \
    __builtin_amdgcn_s_setprio(0);                                        \
    TAILWAIT;                                                             \
    BAR;                                                                  \
  }

  // Prologue: stage tile 0 in wait-order; leave A@64,A@192 in flight.
  stageB(0, 0, 0);
  stageB(0, 0, 64);
  if constexpr (BN_ == 256) {
    stageB(0, 0, 128);
    stageB(0, 0, 192);
  }
  stageA(0, 0, 0);
  stageA(0, 0, 128);
  stageA(0, 0, 64);
  stageA(0, 0, 192);
  VMCNT(2);
  BAR;

  for (int t = 0; t < KT - 1; ++t) {
    const int d = t & 1, o = d ^ 1;
    const int kn = (t + 1) * BK;
    bf16x8 bf[NFRAG][2];
    PHASE0(stageB(o, kn, 0); stageB(o, kn, 64));
    if constexpr (BN_ == 256) {
      PHASE(1, stageB(o, kn, 128); stageB(o, kn, 192), VMCNT(4));
    } else {
      PHASE(1, (void)0, VMCNT(2));
    }
    PHASE(2, stageA(o, kn, 0); stageA(o, kn, 128), (void)0);
    PHASE(3, stageA(o, kn, 64); stageA(o, kn, 192), VMCNT(2));
  }
  {  // peeled last tile: no staging; drain remaining A before P2 reads.
    const int d = (KT - 1) & 1;
    bf16x8 bf[NFRAG][2];
    PHASE0((void)0);
    PHASE(1, (void)0, VMCNT(0));
    PHASE(2, (void)0, (void)0);
    PHASE(3, (void)0, (void)0);
  }
#undef PHASE0
#undef PHASE

  // Epilogue. C frag layout: col = l15, row = l4*4 + j (verified r1-r7).
  // Diag mask and pos capture in GLOBAL coords (valid for any sub-tile).
  float rs[8][4];
  float cs[NFRAG];
#pragma unroll
  for (int m = 0; m < 8; ++m)
#pragma unroll
    for (int j = 0; j < 4; ++j) rs[m][j] = 0.f;
#pragma unroll
  for (int n = 0; n < NFRAG; ++n) cs[n] = 0.f;

#pragma unroll
  for (int m = 0; m < 8; ++m)
#pragma unroll
    for (int n = 0; n < NFRAG; ++n)
#pragma unroll
      for (int j = 0; j < 4; ++j) {
        const int rl = wr * 128 + m * 16 + l4 * 4 + j;
        const int cl = wc * (BN_ / 4) + n * 16 + l15;
        const int grow = rowBase + rl, gcol = colBase + cl;
        const float v = acc[m][n][j];
        float e = __expf(v);
        if (grow == gcol) e = 0.f;  // mask self-similarity
        rs[m][j] += e;
        cs[n] += e;
        if (gcol == grow + BHALF) pos[grow] = v;  // sim[i, i+B]/T
      }

#pragma unroll
  for (int m = 0; m < 8; ++m)
#pragma unroll
    for (int j = 0; j < 4; ++j) {
      float s = rs[m][j];
      s += __shfl_xor(s, 1);
      s += __shfl_xor(s, 2);
      s += __shfl_xor(s, 4);
      s += __shfl_xor(s, 8);
      if (l15 == 0) atomicAdd(&lds_rsum[wr * 128 + m * 16 + l4 * 4 + j], s);
    }
  if (rowBase != colBase) {  // off-diagonal: scatter transpose col-sums
#pragma unroll
    for (int n = 0; n < NFRAG; ++n) {
      float s = cs[n];
      s += __shfl_xor(s, 16);
      s += __shfl_xor(s, 32);
      if (l4 == 0) atomicAdd(&lds_csum[wc * (BN_ / 4) + n * 16 + l15], s);
    }
  }
  __syncthreads();
  if (tid < BM) atomicAdd(&rowsum[rowBase + tid], lds_rsum[tid]);
  if (rowBase != colBase && tid < BN_)
    atomicAdd(&rowsum[colBase + tid], lds_csum[tid]);
}

// ---------------------------------------------------------------------------
// Kernel 2: triangular fused sim/exp/row-sum. NO fences, NO done-counter
// (r7 bisect: agent-scope fence/atomic tail invalidates per-XCD L2s chip-
// wide -> 3.8x regression). Blocks 0..511: full tiles; 512..543: N-halves
// of the 16 leftover tiles, dispatched last to backfill the makespan tail.
// ---------------------------------------------------------------------------
__global__ __launch_bounds__(512) void simexp_tri_kernel(
    const unsigned short* __restrict__ fn, float* __restrict__ rowsum,
    float* __restrict__ pos) {
  const int bid = (int)blockIdx.x;
  const bool half = (bid >= NFULL);
  int beta, colOff = 0;
  if (!half) {
    const int b = (bid & 7) * (NFULL / 8) + (bid >> 3);  // XCD-contiguous
    beta = (b == 1) ? 527 : b;
  } else {
    const int hb = bid - NFULL;
    const int t = NFULL + (hb >> 1);
    beta = (t == 527) ? 1 : t;
    colOff = (hb & 1) * 128;
  }
  // beta -> (rm, cn): strip enumeration from bottom-right corner.
  int k = (int)((sqrtf(8.f * (float)beta + 1.f) - 1.f) * 0.5f);
  while ((k + 1) * (k + 2) / 2 <= beta) ++k;
  while (k * (k + 1) / 2 > beta) --k;
  const int rm = (NT - 1) - k;
  const int cn = (NT - 1) - (beta - k * (k + 1) / 2);
  const int rowBase = rm * BM, colBase = cn * BM + colOff;

  if (!half)
    tile_body<256>(fn, rowsum, pos, rowBase, colBase);
  else
    tile_body<128>(fn, rowsum, pos, rowBase, colBase);
}

// ---------------------------------------------------------------------------
// Kernel 3: loss += mean-part of ( log(rowsum[i]) - pos[i mod B] ), 32 blocks.
// ---------------------------------------------------------------------------
__global__ __launch_bounds__(256) void reduce_kernel(
    const float* __restrict__ rowsum, const float* __restrict__ pos,
    float* __restrict__ out) {
  __shared__ float part[4];
  const int i = blockIdx.x * 256 + threadIdx.x;
  float a = __logf(rowsum[i]) - pos[i & (BHALF - 1)];
#pragma unroll
  for (int m = 1; m < 64; m <<= 1) a += __shfl_xor(a, m);
  const int w = threadIdx.x >> 6, lane = threadIdx.x & 63;
  if (lane == 0) part[w] = a;
  __syncthreads();
  if (threadIdx.x == 0)
    atomicAdd(out, (part[0] + part[1] + part[2] + part[3]) * (1.0f / NROWS));
}

// ---------------------------------------------------------------------------
extern "C" void kernel_launch(void* const* d_in, const int* in_sizes, int n_in,
                              void* d_out, int out_size, void* d_ws, size_t ws_size,
                              hipStream_t stream) {
  const float* logits = (const float*)d_in[0];
  const float* label = (const float*)d_in[1];
  float* out = (float*)d_out;
  unsigned short* fn = (unsigned short*)d_ws;                        // 8 MB bf16
  float* rowsum = (float*)((char*)d_ws + (size_t)NROWS * DDIM * 2);  // 32 KB
  float* pos = rowsum + NROWS;                                       // 16 KB

  normalize_kernel<<<NROWS / 4, 256, 0, stream>>>(logits, label, fn, rowsum, out);
  simexp_tri_kernel<<<GRID, 512, 2 * 65536, stream>>>(fn, rowsum, pos);
  reduce_kernel<<<NROWS / 256, 256, 0, stream>>>(rowsum, pos, out);
}